// Round 2
// baseline (505.581 us; speedup 1.0000x reference)
//
#include <hip/hip_runtime.h>
#include <math.h>

#define NSAMP 8
#define CH 64
#define HH 64
#define WW 64
#define SPATIAL 4096        // HH*WW
#define PER_SAMPLE 262144   // CH*SPATIAL
#define NTOK 32768          // NSAMP*SPATIAL
#define NHEADS 4
#define HD 16
#define KS 7
#define EPS 1e-5f
#define QSCALE 0.25f        // HD^-0.5

// ---------------- K1: per-sample sum / sumsq ----------------
__global__ __launch_bounds__(256) void k_stats(const float* __restrict__ x,
                                               float* __restrict__ stats) {
    int blk = blockIdx.x;           // 256 blocks: 8 samples x 32 chunks
    int n = blk >> 5, chunk = blk & 31;
    const float4* p4 = (const float4*)(x + n * PER_SAMPLE + chunk * 8192);
    int t = threadIdx.x;
    float s1 = 0.f, s2 = 0.f;
#pragma unroll
    for (int i = 0; i < 8; i++) {
        float4 v = p4[t + i * 256];
        s1 += v.x + v.y + v.z + v.w;
        s2 += v.x * v.x + v.y * v.y + v.z * v.z + v.w * v.w;
    }
#pragma unroll
    for (int off = 1; off < 64; off <<= 1) {
        s1 += __shfl_xor(s1, off);
        s2 += __shfl_xor(s2, off);
    }
    __shared__ float r1[4], r2[4];
    int lane = t & 63, wv = t >> 6;
    if (lane == 0) { r1[wv] = s1; r2[wv] = s2; }
    __syncthreads();
    if (t == 0) {
        atomicAdd(&stats[n * 2 + 0], r1[0] + r1[1] + r1[2] + r1[3]);
        atomicAdd(&stats[n * 2 + 1], r2[0] + r2[1] + r2[2] + r2[3]);
    }
}

// ---------------- K2: norm + QKV GEMM (float4 stores) ----------------
// block = 64 consecutive tokens of one sample; thread: token = t&63, jg = t>>6
__global__ __launch_bounds__(256) void k_qkv(const float* __restrict__ x,
                                             const float* __restrict__ stats,
                                             const float* __restrict__ gn_w,
                                             const float* __restrict__ gn_b,
                                             const float* __restrict__ qkv_w,
                                             const float* __restrict__ qkv_b,
                                             float* __restrict__ qkv) {
    int s0 = blockIdx.x * 64;
    int n = s0 >> 12, sp = s0 & 4095;
    int t = threadIdx.x, tok = t & 63, jg = t >> 6;
    float mu = stats[2 * n] * (1.f / (float)PER_SAMPLE);
    float var = stats[2 * n + 1] * (1.f / (float)PER_SAMPLE) - mu * mu;
    float rstd = rsqrtf(var + EPS);

    const float* xp = x + n * PER_SAMPLE + sp + tok;
    float xv[64];
#pragma unroll
    for (int c = 0; c < 64; c++)
        xv[c] = (xp[c * SPATIAL] - mu) * rstd * gn_w[c] + gn_b[c];

    int j0 = jg * 48;
    float4* op = (float4*)(qkv + (size_t)(s0 + tok) * 192 + j0);
    for (int kb = 0; kb < 12; kb++) {
        float s[4];
#pragma unroll
        for (int u = 0; u < 4; u++) {
            int j = j0 + kb * 4 + u;
            const float* wr = qkv_w + j * 64;
            float ss = qkv_b[j];
#pragma unroll
            for (int c = 0; c < 64; c++) ss += xv[c] * wr[c];
            s[u] = ss;
        }
        if (j0 + kb * 4 < 64) {   // q rows, wave-uniform predicate
            s[0] *= QSCALE; s[1] *= QSCALE; s[2] *= QSCALE; s[3] *= QSCALE;
        }
        op[kb] = make_float4(s[0], s[1], s[2], s[3]);
    }
}

// ---------------- K3: neighborhood attention + proj + residual (fused) ----------------
// block = one (sample,row): 4 waves = 4 heads, lane = column
__global__ __launch_bounds__(256) void k_attnproj(const float* __restrict__ qkv,
                                                  const float* __restrict__ rpb,
                                                  const float* __restrict__ proj_w,
                                                  const float* __restrict__ proj_b,
                                                  const float* __restrict__ x,
                                                  float* __restrict__ y) {
    __shared__ float la[64 * 64];   // [c][tok], 16 KB, conflict-free (c uniform)
    int b = blockIdx.x;             // 512 = 8 samples * 64 rows
    int n = b >> 6, h = b & 63;
    int t = threadIdx.x, head = t >> 6, w = t & 63;
    int tokg = (n * 64 + h) * 64 + w;

    const float4* qp = (const float4*)(qkv + (size_t)tokg * 192 + head * 16);
    float q[16];
#pragma unroll
    for (int i = 0; i < 4; i++) {
        float4 v = qp[i];
        q[4 * i] = v.x; q[4 * i + 1] = v.y; q[4 * i + 2] = v.z; q[4 * i + 3] = v.w;
    }
    int sh = min(max(h - 3, 0), HH - KS);
    int sw = min(max(w - 3, 0), WW - KS);

    float lg[49];
    float mx = -1e30f;
#pragma unroll
    for (int a = 0; a < 7; a++) {
        int row = sh + a;
        int rh = h - sh + 6 - a;
        const float* rp = rpb + (head * 13 + rh) * 13;
#pragma unroll
        for (int bb = 0; bb < 7; bb++) {
            int col = sw + bb;
            const float4* kp = (const float4*)(qkv + (size_t)((n * 64 + row) * 64 + col) * 192 + 64 + head * 16);
            float4 k0 = kp[0], k1 = kp[1], k2 = kp[2], k3 = kp[3];
            float d = q[0] * k0.x + q[1] * k0.y + q[2] * k0.z + q[3] * k0.w
                    + q[4] * k1.x + q[5] * k1.y + q[6] * k1.z + q[7] * k1.w
                    + q[8] * k2.x + q[9] * k2.y + q[10] * k2.z + q[11] * k2.w
                    + q[12] * k3.x + q[13] * k3.y + q[14] * k3.z + q[15] * k3.w;
            int rw = w - sw + 6 - bb;
            d += rp[rw];
            lg[a * 7 + bb] = d;
            mx = fmaxf(mx, d);
        }
    }
    float sum = 0.f;
#pragma unroll
    for (int i = 0; i < 49; i++) {
        float e = __expf(lg[i] - mx);
        lg[i] = e;
        sum += e;
    }
    float rs = 1.f / sum;

    float acc[16];
#pragma unroll
    for (int i = 0; i < 16; i++) acc[i] = 0.f;
#pragma unroll
    for (int a = 0; a < 7; a++) {
        int row = sh + a;
#pragma unroll
        for (int bb = 0; bb < 7; bb++) {
            int col = sw + bb;
            const float4* vp = (const float4*)(qkv + (size_t)((n * 64 + row) * 64 + col) * 192 + 128 + head * 16);
            float p = lg[a * 7 + bb];
            float4 v0 = vp[0], v1 = vp[1], v2 = vp[2], v3 = vp[3];
            acc[0] += p * v0.x; acc[1] += p * v0.y; acc[2] += p * v0.z; acc[3] += p * v0.w;
            acc[4] += p * v1.x; acc[5] += p * v1.y; acc[6] += p * v1.z; acc[7] += p * v1.w;
            acc[8] += p * v2.x; acc[9] += p * v2.y; acc[10] += p * v2.z; acc[11] += p * v2.w;
            acc[12] += p * v3.x; acc[13] += p * v3.y; acc[14] += p * v3.z; acc[15] += p * v3.w;
        }
    }
    // stage attn output in LDS, transposed [c][tok]: c uniform -> conflict-free
#pragma unroll
    for (int i = 0; i < 16; i++)
        la[(head * 16 + i) * 64 + w] = acc[i] * rs;
    __syncthreads();

    // proj phase: tok = w, cg = head (each thread computes 16 output channels)
    float av[64];
#pragma unroll
    for (int c = 0; c < 64; c++) av[c] = la[c * 64 + w];

    const float* xr = x + n * PER_SAMPLE + h * 64 + w;
    float4* yp = (float4*)(y + (size_t)tokg * 64 + head * 16);
    for (int kb = 0; kb < 4; kb++) {
        float s[4];
#pragma unroll
        for (int u = 0; u < 4; u++) {
            int c = head * 16 + kb * 4 + u;
            const float* wr = proj_w + c * 64;
            float ss = proj_b[c];
#pragma unroll
            for (int cc = 0; cc < 64; cc++) ss += av[cc] * wr[cc];
            s[u] = ss + xr[(size_t)c * SPATIAL];   // + x1 residual (NCHW read)
        }
        yp[kb] = make_float4(s[0], s[1], s[2], s[3]);
    }
}

// ---------------- K4: fused LN + fc1 + GELU + fc2 + residual + NCHW store ----------------
// block = 64 tokens, LDS hidden [j][tok] = 256x64 fp32 = 64 KB (conflict-free, j uniform)
__global__ __launch_bounds__(256) void k_mlp(const float* __restrict__ y,
                                             const float* __restrict__ ln_w,
                                             const float* __restrict__ ln_b,
                                             const float* __restrict__ fc1_w,
                                             const float* __restrict__ fc1_b,
                                             const float* __restrict__ fc2_w,
                                             const float* __restrict__ fc2_b,
                                             float* __restrict__ out) {
    __shared__ float lh[256 * 64];  // exactly 64 KB -> 2 blocks/CU
    int s0 = blockIdx.x * 64;
    int n = s0 >> 12, sp = s0 & 4095;
    int t = threadIdx.x, tok = t & 63, g = t >> 6;

    // load y row, layernorm in place
    float yv[64];
    const float4* yp = (const float4*)(y + (size_t)(s0 + tok) * 64);
#pragma unroll
    for (int i = 0; i < 16; i++) {
        float4 v = yp[i];
        yv[4 * i] = v.x; yv[4 * i + 1] = v.y; yv[4 * i + 2] = v.z; yv[4 * i + 3] = v.w;
    }
    float mu = 0.f;
#pragma unroll
    for (int c = 0; c < 64; c++) mu += yv[c];
    mu *= (1.f / 64.f);
    float var = 0.f;
#pragma unroll
    for (int c = 0; c < 64; c++) { float d = yv[c] - mu; var += d * d; }
    var *= (1.f / 64.f);
    float rstd = rsqrtf(var + EPS);
#pragma unroll
    for (int c = 0; c < 64; c++)
        yv[c] = (yv[c] - mu) * rstd * ln_w[c] + ln_b[c];

    // phase 1: fc1 + exact GELU -> LDS (64 j-values per thread)
    int j0 = g * 64;
    for (int k = 0; k < 64; k++) {
        int j = j0 + k;
        const float* wr = fc1_w + j * 64;
        float s = fc1_b[j];
#pragma unroll
        for (int c = 0; c < 64; c++) s += yv[c] * wr[c];
        lh[j * 64 + tok] = 0.5f * s * (1.f + erff(s * 0.70710678118654752f));
    }
    __syncthreads();

    // phase 2: fc2 (16 channels per thread), j loop over 256 hidden
    float acc[16];
#pragma unroll
    for (int k = 0; k < 16; k++) acc[k] = 0.f;
    for (int j = 0; j < 256; j++) {
        float hj = lh[j * 64 + tok];
        const float* wc = fc2_w + j;    // column j; rows stride 256
#pragma unroll
        for (int k = 0; k < 16; k++)
            acc[k] += hj * wc[(size_t)(g * 16 + k) * 256];
    }

    // epilogue: + fc2_b + y residual (reload 16 values), NCHW coalesced store
    const float* yres = y + (size_t)(s0 + tok) * 64 + g * 16;
    float* op = out + (size_t)n * PER_SAMPLE + sp + tok;
#pragma unroll
    for (int k = 0; k < 16; k++) {
        int c = g * 16 + k;
        op[(size_t)c * SPATIAL] = acc[k] + fc2_b[c] + yres[k];
    }
}

extern "C" void kernel_launch(void* const* d_in, const int* in_sizes, int n_in,
                              void* d_out, int out_size, void* d_ws, size_t ws_size,
                              hipStream_t stream) {
    const float* x      = (const float*)d_in[0];
    const float* gn_w   = (const float*)d_in[1];
    const float* gn_b   = (const float*)d_in[2];
    const float* qkv_w  = (const float*)d_in[3];
    const float* qkv_b  = (const float*)d_in[4];
    const float* rpb    = (const float*)d_in[5];
    const float* proj_w = (const float*)d_in[6];
    const float* proj_b = (const float*)d_in[7];
    const float* ln_w   = (const float*)d_in[8];
    const float* ln_b   = (const float*)d_in[9];
    const float* fc1_w  = (const float*)d_in[10];
    const float* fc1_b  = (const float*)d_in[11];
    const float* fc2_w  = (const float*)d_in[12];
    const float* fc2_b  = (const float*)d_in[13];
    float* out = (float*)d_out;

    float* ws    = (float*)d_ws;
    float* stats = ws;                       // 16 floats
    float* qkv   = ws + 64;                  // 32768*192 floats = 25.2 MB
    float* y     = qkv + (size_t)NTOK * 192; // 32768*64 floats  = 8.4 MB

    hipMemsetAsync(stats, 0, 64, stream);
    k_stats   <<<256, 256, 0, stream>>>(x, stats);
    k_qkv     <<<512, 256, 0, stream>>>(x, stats, gn_w, gn_b, qkv_w, qkv_b, qkv);
    k_attnproj<<<512, 256, 0, stream>>>(qkv, rpb, proj_w, proj_b, x, y);
    k_mlp     <<<512, 256, 0, stream>>>(y, ln_w, ln_b, fc1_w, fc1_b, fc2_w, fc2_b, out);
}

// Round 3
// 272.903 us; speedup vs baseline: 1.8526x; 1.8526x over previous
//
#include <hip/hip_runtime.h>
#include <math.h>

#define NSAMP 8
#define CH 64
#define HH 64
#define WW 64
#define SPATIAL 4096        // HH*WW
#define PER_SAMPLE 262144   // CH*SPATIAL
#define NTOK 32768          // NSAMP*SPATIAL
#define NHEADS 4
#define HD 16
#define KS 7
#define EPS 1e-5f
#define QSCALE 0.25f        // HD^-0.5

// qkv_t layout: [c'][token], c' in [0,192): 0-63 q (head*16+d), 64-127 k, 128-191 v
// y_t   layout: [c][token], c in [0,64)
// token = n*4096 + h*64 + w  (lane = w -> coalesced everywhere)

// ---------------- K1: per-sample sum / sumsq ----------------
__global__ __launch_bounds__(256) void k_stats(const float* __restrict__ x,
                                               float* __restrict__ stats) {
    int blk = blockIdx.x;           // 256 blocks: 8 samples x 32 chunks
    int n = blk >> 5, chunk = blk & 31;
    const float4* p4 = (const float4*)(x + n * PER_SAMPLE + chunk * 8192);
    int t = threadIdx.x;
    float s1 = 0.f, s2 = 0.f;
#pragma unroll
    for (int i = 0; i < 8; i++) {
        float4 v = p4[t + i * 256];
        s1 += v.x + v.y + v.z + v.w;
        s2 += v.x * v.x + v.y * v.y + v.z * v.z + v.w * v.w;
    }
#pragma unroll
    for (int off = 1; off < 64; off <<= 1) {
        s1 += __shfl_xor(s1, off);
        s2 += __shfl_xor(s2, off);
    }
    __shared__ float r1[4], r2[4];
    int lane = t & 63, wv = t >> 6;
    if (lane == 0) { r1[wv] = s1; r2[wv] = s2; }
    __syncthreads();
    if (t == 0) {
        atomicAdd(&stats[n * 2 + 0], r1[0] + r1[1] + r1[2] + r1[3]);
        atomicAdd(&stats[n * 2 + 1], r2[0] + r2[1] + r2[2] + r2[3]);
    }
}

// ---------------- K2: norm + QKV GEMM -> channel-major qkv_t ----------------
__global__ __launch_bounds__(256) void k_qkv(const float* __restrict__ x,
                                             const float* __restrict__ stats,
                                             const float* __restrict__ gn_w,
                                             const float* __restrict__ gn_b,
                                             const float* __restrict__ qkv_w,
                                             const float* __restrict__ qkv_b,
                                             float* __restrict__ qkv) {
    int s0 = blockIdx.x * 64;       // 64 consecutive tokens (one image row)
    int n = s0 >> 12;
    int t = threadIdx.x, tok = t & 63;
    int jg = __builtin_amdgcn_readfirstlane(t >> 6);   // provably wave-uniform
    float mu = stats[2 * n] * (1.f / (float)PER_SAMPLE);
    float var = stats[2 * n + 1] * (1.f / (float)PER_SAMPLE) - mu * mu;
    float rstd = rsqrtf(var + EPS);

    const float* xp = x + n * PER_SAMPLE + (s0 & 4095) + tok;
    float xv[64];
#pragma unroll
    for (int c = 0; c < 64; c++)
        xv[c] = (xp[c * SPATIAL] - mu) * rstd * gn_w[c] + gn_b[c];

    int j0 = jg * 48;
    for (int k = 0; k < 48; k++) {
        int j = j0 + k;                      // uniform -> s_load weight row
        const float* wr = qkv_w + j * 64;
        float s = qkv_b[j];
#pragma unroll
        for (int c = 0; c < 64; c++) s = fmaf(xv[c], wr[c], s);
        if (j < 64) s *= QSCALE;             // q rows pre-scaled
        qkv[(size_t)j * NTOK + s0 + tok] = s;   // coalesced dword store
    }
}

// ---------------- K3: neighborhood attention + proj + residual ----------------
// block = one (sample,row); wave = head, lane = column
__global__ __launch_bounds__(256) void k_attnproj(const float* __restrict__ qkv,
                                                  const float* __restrict__ rpb,
                                                  const float* __restrict__ proj_w,
                                                  const float* __restrict__ proj_b,
                                                  const float* __restrict__ x,
                                                  float* __restrict__ y) {
    __shared__ float la[64 * 64];   // attn out [c][w], conflict-free
    int b = blockIdx.x;             // 512 = 8 samples * 64 rows
    int n = b >> 6, h = b & 63;
    int t = threadIdx.x, w = t & 63;
    int head = __builtin_amdgcn_readfirstlane(t >> 6);
    int rowbase = n * 4096 + h * 64;

    float q[16];
#pragma unroll
    for (int d = 0; d < 16; d++)
        q[d] = qkv[(size_t)(head * 16 + d) * NTOK + rowbase + w];  // coalesced

    int sh = min(max(h - 3, 0), HH - KS);
    int sw = min(max(w - 3, 0), WW - KS);

    float lg[49];
    float mx = -1e30f;
#pragma unroll
    for (int a = 0; a < 7; a++) {
        int nb = n * 4096 + (sh + a) * 64 + sw;
        int rh = h - sh + 6 - a;
        const float* rp = rpb + (head * 13 + rh) * 13;
#pragma unroll
        for (int bb = 0; bb < 7; bb++) {
            int col = nb + bb;
            float d = 0.f;
#pragma unroll
            for (int dd = 0; dd < 16; dd++)
                d = fmaf(q[dd], qkv[(size_t)(64 + head * 16 + dd) * NTOK + col], d);
            d += rp[w - sw + 6 - bb];
            lg[a * 7 + bb] = d;
            mx = fmaxf(mx, d);
        }
    }
    float sum = 0.f;
#pragma unroll
    for (int i = 0; i < 49; i++) {
        float e = __expf(lg[i] - mx);
        lg[i] = e;
        sum += e;
    }
    float rs = 1.f / sum;

    float acc[16];
#pragma unroll
    for (int i = 0; i < 16; i++) acc[i] = 0.f;
#pragma unroll
    for (int a = 0; a < 7; a++) {
        int nb = n * 4096 + (sh + a) * 64 + sw;
#pragma unroll
        for (int bb = 0; bb < 7; bb++) {
            int col = nb + bb;
            float p = lg[a * 7 + bb];
#pragma unroll
            for (int dd = 0; dd < 16; dd++)
                acc[dd] = fmaf(p, qkv[(size_t)(128 + head * 16 + dd) * NTOK + col], acc[dd]);
        }
    }
#pragma unroll
    for (int i = 0; i < 16; i++)
        la[(head * 16 + i) * 64 + w] = acc[i] * rs;
    __syncthreads();

    // proj: thread computes 16 output channels for token w
    float av[64];
#pragma unroll
    for (int c = 0; c < 64; c++) av[c] = la[c * 64 + w];

    const float* xr = x + n * PER_SAMPLE + h * 64 + w;
    for (int k = 0; k < 16; k++) {
        int c = head * 16 + k;               // uniform -> s_load weight row
        const float* wr = proj_w + c * 64;
        float s = proj_b[c];
#pragma unroll
        for (int cc = 0; cc < 64; cc++) s = fmaf(av[cc], wr[cc], s);
        s += xr[(size_t)c * SPATIAL];        // + x residual (coalesced)
        y[(size_t)c * NTOK + rowbase + w] = s;  // coalesced dword store
    }
}

// ---------------- K4: LN + fc1 + GELU + fc2 + residual + NCHW store ----------------
// 32 KB LDS: yn [64][64] + hidden chunk [64][64]; 4 chunks of 64 hidden units
__global__ __launch_bounds__(256) void k_mlp(const float* __restrict__ y,
                                             const float* __restrict__ ln_w,
                                             const float* __restrict__ ln_b,
                                             const float* __restrict__ fc1_w,
                                             const float* __restrict__ fc1_b,
                                             const float* __restrict__ fc2_w,
                                             const float* __restrict__ fc2_b,
                                             float* __restrict__ out) {
    __shared__ float yn[64 * 64];   // normalized y [c][tok]
    __shared__ float lh[64 * 64];   // hidden chunk [jloc][tok]
    __shared__ float red1[256], red2[256];
    int s0 = blockIdx.x * 64;
    int n = s0 >> 12, sp = s0 & 4095;
    int t = threadIdx.x, tok = t & 63;
    int g = __builtin_amdgcn_readfirstlane(t >> 6);

    // --- LN: thread owns 16 channels of its token-quarter ---
    float yv[16];
    float s1 = 0.f, s2 = 0.f;
#pragma unroll
    for (int k = 0; k < 16; k++) {
        float v = y[(size_t)(g * 16 + k) * NTOK + s0 + tok];   // coalesced
        yv[k] = v; s1 += v; s2 += v * v;
    }
    red1[g * 64 + tok] = s1;
    red2[g * 64 + tok] = s2;
    __syncthreads();
    float mu = (red1[tok] + red1[64 + tok] + red1[128 + tok] + red1[192 + tok]) * (1.f / 64.f);
    float sq = (red2[tok] + red2[64 + tok] + red2[128 + tok] + red2[192 + tok]) * (1.f / 64.f);
    float rstd = rsqrtf(sq - mu * mu + EPS);
#pragma unroll
    for (int k = 0; k < 16; k++) {
        int c = g * 16 + k;                  // uniform -> scalar ln_w/ln_b
        yn[c * 64 + tok] = (yv[k] - mu) * rstd * ln_w[c] + ln_b[c];
    }
    __syncthreads();

    float acc[16];
#pragma unroll
    for (int k = 0; k < 16; k++) acc[k] = 0.f;

    for (int jc = 0; jc < 4; jc++) {
        // phase 1: 16 fc1 rows per thread for this 64-wide hidden chunk
        {
            float ynr[64];
#pragma unroll
            for (int c = 0; c < 64; c++) ynr[c] = yn[c * 64 + tok];
            for (int k = 0; k < 16; k++) {
                int j = jc * 64 + g * 16 + k;        // uniform -> s_load row
                const float* wr = fc1_w + j * 64;
                float s = fc1_b[j];
#pragma unroll
                for (int c = 0; c < 64; c++) s = fmaf(ynr[c], wr[c], s);
                lh[(g * 16 + k) * 64 + tok] = 0.5f * s * (1.f + erff(s * 0.70710678118654752f));
            }
        }
        __syncthreads();
        // phase 2: accumulate this chunk into 16 fc2 outputs per thread
        {
            float hv[64];
#pragma unroll
            for (int j = 0; j < 64; j++) hv[j] = lh[j * 64 + tok];
            for (int k = 0; k < 16; k++) {
                int c = g * 16 + k;                  // uniform -> s_load row
                const float* wr = fc2_w + (size_t)c * 256 + jc * 64;
                float s = acc[k];
#pragma unroll
                for (int j = 0; j < 64; j++) s = fmaf(hv[j], wr[j], s);
                acc[k] = s;
            }
        }
        __syncthreads();
    }

    // epilogue: + bias + residual, NCHW coalesced store
    float* op = out + (size_t)n * PER_SAMPLE + sp + tok;
#pragma unroll
    for (int k = 0; k < 16; k++) {
        int c = g * 16 + k;
        float r = y[(size_t)c * NTOK + s0 + tok];    // residual reload (L2 hit)
        op[(size_t)c * SPATIAL] = acc[k] + fc2_b[c] + r;
    }
}

extern "C" void kernel_launch(void* const* d_in, const int* in_sizes, int n_in,
                              void* d_out, int out_size, void* d_ws, size_t ws_size,
                              hipStream_t stream) {
    const float* x      = (const float*)d_in[0];
    const float* gn_w   = (const float*)d_in[1];
    const float* gn_b   = (const float*)d_in[2];
    const float* qkv_w  = (const float*)d_in[3];
    const float* qkv_b  = (const float*)d_in[4];
    const float* rpb    = (const float*)d_in[5];
    const float* proj_w = (const float*)d_in[6];
    const float* proj_b = (const float*)d_in[7];
    const float* ln_w   = (const float*)d_in[8];
    const float* ln_b   = (const float*)d_in[9];
    const float* fc1_w  = (const float*)d_in[10];
    const float* fc1_b  = (const float*)d_in[11];
    const float* fc2_w  = (const float*)d_in[12];
    const float* fc2_b  = (const float*)d_in[13];
    float* out = (float*)d_out;

    float* ws    = (float*)d_ws;
    float* stats = ws;                        // 16 floats
    float* qkv   = ws + 64;                   // 192 * 32768 floats (channel-major)
    float* y     = qkv + (size_t)192 * NTOK;  // 64 * 32768 floats (channel-major)

    hipMemsetAsync(stats, 0, 64, stream);
    k_stats   <<<256, 256, 0, stream>>>(x, stats);
    k_qkv     <<<512, 256, 0, stream>>>(x, stats, gn_w, gn_b, qkv_w, qkv_b, qkv);
    k_attnproj<<<512, 256, 0, stream>>>(qkv, rpb, proj_w, proj_b, x, y);
    k_mlp     <<<512, 256, 0, stream>>>(y, ln_w, ln_b, fc1_w, fc1_b, fc2_w, fc2_b, out);
}